// Round 2
// baseline (9551.413 us; speedup 1.0000x reference)
//
#include <hip/hip_runtime.h>
#include <stdint.h>

typedef unsigned long long ull;

#define VOCAB   50000
#define EMBD    512
#define HID     1024
#define SEQ     2048
#define OUTD    5
#define MAXLEN  20
#define SOSTOK  1
#define EOSTOK  2

#define NBLK 256
#define NTHR 256

#define DONEBIT 0x40000000u
#define TAGMSK  0x3FFFFFFFu
#define SPINMAX (1 << 22)

// Bounded spin: poll *p until (tag & msk) == tg. Bound turns a protocol bug
// into a fast wrong-answer instead of a device hang.
#define SPIN(v, p, tg, msk) \
  { int _n = 0; while (((unsigned)((v) >> 32) & (msk)) != (tg)) { (v) = ldA(p); if (++_n > SPINMAX) break; } }

// LDS: double-buffered h and e vectors (parity = step), XOR-swizzled at
// float4 granularity so per-lane 64B-strided b128 reads are conflict-free.
struct alignas(16) SharedR {
  float h[2][HID];
  float e[2][EMBD];
  float predv[OUTD];
  int   nid;
  int   sdone;
};

__device__ __forceinline__ float sigf(float x)      { return 1.0f / (1.0f + __expf(-x)); }
__device__ __forceinline__ float tanh_fast(float x) { return 1.0f - 2.0f / (__expf(2.0f * x) + 1.0f); }

// Tagged-cell ops: AGENT scope -> coherent across XCDs (bypasses stale L1/L2).
__device__ __forceinline__ ull ldA(ull* p) {
  return __hip_atomic_load(p, __ATOMIC_RELAXED, __HIP_MEMORY_SCOPE_AGENT);
}
__device__ __forceinline__ void stA(ull* p, ull v) {
  __hip_atomic_store(p, v, __ATOMIC_RELAXED, __HIP_MEMORY_SCOPE_AGENT);
}

__global__ __launch_bounds__(NTHR, 1) void s2s_kernel(
    const int*   __restrict__ x,
    const float* __restrict__ emb,
    const float* __restrict__ eWih, const float* __restrict__ eWhh,
    const float* __restrict__ ebih, const float* __restrict__ ebhh,
    const float* __restrict__ dWih, const float* __restrict__ dWhh,
    const float* __restrict__ dbih, const float* __restrict__ dbhh,
    const float* __restrict__ oW,   const float* __restrict__ ob,
    float* __restrict__ out, char* __restrict__ ws)
{
  const int b   = blockIdx.x;
  const int tid = threadIdx.x;
  const int wv  = tid >> 6;
  const int ln  = tid & 63;
  const int j   = 4 * b + wv;          // h index owned by this wave (0..1023)

  // Double-buffered tagged cells (parity = tag&1): no producer can overwrite
  // a buffer until every block has consumed the previous tag in it.
  ull* hp = (ull*)ws;                        // [2][HID]  (tag<<32)|h_bits
  ull* ep = (ull*)(ws + 2 * HID * 8);        // [2][EMBD] (tag<<32)|e_bits

  __shared__ SharedR sh;

  // ---- encoder weights resident in registers for the whole recurrence ----
  float wr[4][16];   // eWhh[g*HID+j][16*ln + m]
  float wi[4][8];    // eWih[g*HID+j][ 8*ln + m]
  #pragma unroll
  for (int g = 0; g < 4; ++g) {
    const float4* ph = (const float4*)&eWhh[(size_t)(g * HID + j) * HID + ln * 16];
    #pragma unroll
    for (int q = 0; q < 4; ++q) {
      float4 v = ph[q];
      wr[g][q*4+0] = v.x; wr[g][q*4+1] = v.y; wr[g][q*4+2] = v.z; wr[g][q*4+3] = v.w;
    }
    const float4* pw = (const float4*)&eWih[(size_t)(g * HID + j) * EMBD + ln * 8];
    #pragma unroll
    for (int q = 0; q < 2; ++q) {
      float4 v = pw[q];
      wi[g][q*4+0] = v.x; wi[g][q*4+1] = v.y; wi[g][q*4+2] = v.z; wi[g][q*4+3] = v.w;
    }
  }
  float bse[4], bsd[4];
  if (ln == 0) {
    #pragma unroll
    for (int g = 0; g < 4; ++g) {
      int r = g * HID + j;
      bse[g] = ebih[r] + ebhh[r];
      bsd[g] = dbih[r] + dbhh[r];
    }
  }

  // h0 = 0
  for (int i = tid; i < HID; i += NTHR) sh.h[0][i] = 0.f;
  float creg = 0.f;                    // cell state (lane 0 of each wave)

  // ============================ ENCODER ============================
  #pragma unroll 1
  for (int t = 1; t <= SEQ; ++t) {
    // embedding fetch for this step (overlaps the h poll). emb[PAD] is all-zero.
    int xv = x[t - 1];
    float2 ein = *(const float2*)&emb[(size_t)xv * EMBD + tid * 2];

    if (t > 1) {                       // poll h_{t-1} from buffer (t-1)&1
      unsigned tg = (unsigned)(t - 1);
      ull* hb = hp + ((t - 1) & 1) * HID;
      int c = tid * 4;
      ull v0 = ldA(&hb[c+0]), v1 = ldA(&hb[c+1]), v2 = ldA(&hb[c+2]), v3 = ldA(&hb[c+3]);
      SPIN(v0, &hb[c+0], tg, 0xFFFFFFFFu);
      SPIN(v1, &hb[c+1], tg, 0xFFFFFFFFu);
      SPIN(v2, &hb[c+2], tg, 0xFFFFFFFFu);
      SPIN(v3, &hb[c+3], tg, 0xFFFFFFFFu);
      float4 hv4;
      hv4.x = __uint_as_float((unsigned)v0);
      hv4.y = __uint_as_float((unsigned)v1);
      hv4.z = __uint_as_float((unsigned)v2);
      hv4.w = __uint_as_float((unsigned)v3);
      ((float4*)sh.h[(t - 1) & 1])[tid ^ ((tid >> 2) & 7)] = hv4;
    }
    {
      float* eb = sh.e[(t - 1) & 1];
      int gp = (tid >> 1) ^ ((tid >> 3) & 7);
      int lo = (tid & 1) * 2;
      eb[gp * 4 + lo + 0] = ein.x;
      eb[gp * 4 + lo + 1] = ein.y;
    }
    __syncthreads();

    const float4* h4 = (const float4*)sh.h[(t - 1) & 1];
    const float4* e4 = (const float4*)sh.e[(t - 1) & 1];
    float hv[16], ev[8];
    #pragma unroll
    for (int q = 0; q < 4; ++q) {
      float4 v = h4[(4 * ln + q) ^ (ln & 7)];
      hv[q*4+0] = v.x; hv[q*4+1] = v.y; hv[q*4+2] = v.z; hv[q*4+3] = v.w;
    }
    #pragma unroll
    for (int q = 0; q < 2; ++q) {
      float4 v = e4[(2 * ln + q) ^ ((ln >> 1) & 7)];
      ev[q*4+0] = v.x; ev[q*4+1] = v.y; ev[q*4+2] = v.z; ev[q*4+3] = v.w;
    }
    float a0 = 0.f, a1 = 0.f, a2 = 0.f, a3 = 0.f;
    #pragma unroll
    for (int m = 0; m < 16; ++m) {
      a0 = fmaf(wr[0][m], hv[m], a0);
      a1 = fmaf(wr[1][m], hv[m], a1);
      a2 = fmaf(wr[2][m], hv[m], a2);
      a3 = fmaf(wr[3][m], hv[m], a3);
    }
    #pragma unroll
    for (int m = 0; m < 8; ++m) {
      a0 = fmaf(wi[0][m], ev[m], a0);
      a1 = fmaf(wi[1][m], ev[m], a1);
      a2 = fmaf(wi[2][m], ev[m], a2);
      a3 = fmaf(wi[3][m], ev[m], a3);
    }
    #pragma unroll
    for (int off = 32; off > 0; off >>= 1) {
      a0 += __shfl_xor(a0, off);
      a1 += __shfl_xor(a1, off);
      a2 += __shfl_xor(a2, off);
      a3 += __shfl_xor(a3, off);
    }
    if (ln == 0) {                      // gate order i,f,g,o
      float iv = sigf(a0 + bse[0]);
      float fv = sigf(a1 + bse[1]);
      float gv = tanh_fast(a2 + bse[2]);
      float ov = sigf(a3 + bse[3]);
      creg = fv * creg + iv * gv;
      float hn = ov * tanh_fast(creg);
      stA(&hp[(t & 1) * HID + j], ((ull)(unsigned)t << 32) | (ull)__float_as_uint(hn));
    }
  }

  // ============================ DECODER ============================
  #pragma unroll 1
  for (int s = 0; s < MAXLEN; ++s) {
    // ---- input embedding ----
    if (s == 0) {
      if (tid < 128) {
        const float4* se = (const float4*)&emb[SOSTOK * EMBD];
        ((float4*)sh.e[0])[tid ^ ((tid >> 2) & 7)] = se[tid];
      }
      if (tid == 0) sh.sdone = 0;
    } else {
      unsigned tg = (unsigned)s;
      ull* eb = ep + (s & 1) * EMBD;
      int c = tid * 2;
      ull v0 = ldA(&eb[c+0]), v1 = ldA(&eb[c+1]);
      SPIN(v0, &eb[c+0], tg, TAGMSK);
      SPIN(v1, &eb[c+1], tg, TAGMSK);
      if (tid == 0) sh.sdone = (((unsigned)(v0 >> 32)) & DONEBIT) ? 1 : 0;
      float* ebl = sh.e[s & 1];
      int gp = (tid >> 1) ^ ((tid >> 3) & 7);
      int lo = (tid & 1) * 2;
      ebl[gp * 4 + lo + 0] = __uint_as_float((unsigned)v0);
      ebl[gp * 4 + lo + 1] = __uint_as_float((unsigned)v1);
    }
    // ---- poll h input (tag SEQ+s, buffer s&1; s=0 reuses encoder-final 2048) ----
    {
      unsigned tg = (unsigned)(SEQ + s);
      ull* hb = hp + (s & 1) * HID;
      int c = tid * 4;
      ull v0 = ldA(&hb[c+0]), v1 = ldA(&hb[c+1]), v2 = ldA(&hb[c+2]), v3 = ldA(&hb[c+3]);
      SPIN(v0, &hb[c+0], tg, 0xFFFFFFFFu);
      SPIN(v1, &hb[c+1], tg, 0xFFFFFFFFu);
      SPIN(v2, &hb[c+2], tg, 0xFFFFFFFFu);
      SPIN(v3, &hb[c+3], tg, 0xFFFFFFFFu);
      float4 hv4;
      hv4.x = __uint_as_float((unsigned)v0);
      hv4.y = __uint_as_float((unsigned)v1);
      hv4.z = __uint_as_float((unsigned)v2);
      hv4.w = __uint_as_float((unsigned)v3);
      ((float4*)sh.h[s & 1])[tid ^ ((tid >> 2) & 7)] = hv4;
    }
    __syncthreads();
    if (s > 0 && sh.sdone) {
      if (b == 0) {   // zero-fill remaining rows + valids, then stop (d_out is poisoned)
        for (int i = s * OUTD + tid; i < OUTD * MAXLEN; i += NTHR) out[i] = 0.f;
        for (int i = s + tid; i < MAXLEN; i += NTHR) out[OUTD * MAXLEN + i] = 0.f;
      }
      break;
    }

    const float4* h4 = (const float4*)sh.h[s & 1];
    const float4* e4 = (const float4*)sh.e[s & 1];
    float hv[16], ev[8];
    #pragma unroll
    for (int q = 0; q < 4; ++q) {
      float4 v = h4[(4 * ln + q) ^ (ln & 7)];
      hv[q*4+0] = v.x; hv[q*4+1] = v.y; hv[q*4+2] = v.z; hv[q*4+3] = v.w;
    }
    #pragma unroll
    for (int q = 0; q < 2; ++q) {
      float4 v = e4[(2 * ln + q) ^ ((ln >> 1) & 7)];
      ev[q*4+0] = v.x; ev[q*4+1] = v.y; ev[q*4+2] = v.z; ev[q*4+3] = v.w;
    }
    float ag[4];
    #pragma unroll
    for (int g = 0; g < 4; ++g) {
      size_t row = (size_t)(g * HID + j);
      const float4* wh = (const float4*)&dWhh[row * HID + ln * 16];
      const float4* wu = (const float4*)&dWih[row * EMBD + ln * 8];
      float4 w0 = wh[0], w1 = wh[1], w2 = wh[2], w3 = wh[3];
      float4 u0 = wu[0], u1 = wu[1];
      float acc = 0.f;
      acc = fmaf(w0.x, hv[ 0], acc); acc = fmaf(w0.y, hv[ 1], acc);
      acc = fmaf(w0.z, hv[ 2], acc); acc = fmaf(w0.w, hv[ 3], acc);
      acc = fmaf(w1.x, hv[ 4], acc); acc = fmaf(w1.y, hv[ 5], acc);
      acc = fmaf(w1.z, hv[ 6], acc); acc = fmaf(w1.w, hv[ 7], acc);
      acc = fmaf(w2.x, hv[ 8], acc); acc = fmaf(w2.y, hv[ 9], acc);
      acc = fmaf(w2.z, hv[10], acc); acc = fmaf(w2.w, hv[11], acc);
      acc = fmaf(w3.x, hv[12], acc); acc = fmaf(w3.y, hv[13], acc);
      acc = fmaf(w3.z, hv[14], acc); acc = fmaf(w3.w, hv[15], acc);
      acc = fmaf(u0.x, ev[ 0], acc); acc = fmaf(u0.y, ev[ 1], acc);
      acc = fmaf(u0.z, ev[ 2], acc); acc = fmaf(u0.w, ev[ 3], acc);
      acc = fmaf(u1.x, ev[ 4], acc); acc = fmaf(u1.y, ev[ 5], acc);
      acc = fmaf(u1.z, ev[ 6], acc); acc = fmaf(u1.w, ev[ 7], acc);
      ag[g] = acc;
    }
    #pragma unroll
    for (int off = 32; off > 0; off >>= 1) {
      ag[0] += __shfl_xor(ag[0], off);
      ag[1] += __shfl_xor(ag[1], off);
      ag[2] += __shfl_xor(ag[2], off);
      ag[3] += __shfl_xor(ag[3], off);
    }
    if (ln == 0) {
      float iv = sigf(ag[0] + bsd[0]);
      float fv = sigf(ag[1] + bsd[1]);
      float gv = tanh_fast(ag[2] + bsd[2]);
      float ov = sigf(ag[3] + bsd[3]);
      creg = fv * creg + iv * gv;
      float hn = ov * tanh_fast(creg);
      stA(&hp[((s + 1) & 1) * HID + j],
          ((ull)(unsigned)(SEQ + 1 + s) << 32) | (ull)__float_as_uint(hn));
    }

    // ---- block 0: output projection, token decision, next-emb publish ----
    if (b == 0) {
      unsigned tg = (unsigned)(SEQ + 1 + s);
      ull* hb = hp + ((s + 1) & 1) * HID;
      int c = tid * 4;
      ull v0 = ldA(&hb[c+0]), v1 = ldA(&hb[c+1]), v2 = ldA(&hb[c+2]), v3 = ldA(&hb[c+3]);
      SPIN(v0, &hb[c+0], tg, 0xFFFFFFFFu);
      SPIN(v1, &hb[c+1], tg, 0xFFFFFFFFu);
      SPIN(v2, &hb[c+2], tg, 0xFFFFFFFFu);
      SPIN(v3, &hb[c+3], tg, 0xFFFFFFFFu);
      float4 hv4;
      hv4.x = __uint_as_float((unsigned)v0);
      hv4.y = __uint_as_float((unsigned)v1);
      hv4.z = __uint_as_float((unsigned)v2);
      hv4.w = __uint_as_float((unsigned)v3);
      ((float4*)sh.h[(s + 1) & 1])[tid ^ ((tid >> 2) & 7)] = hv4;
      __syncthreads();
      if (wv == 0) {
        const float4* nh4 = (const float4*)sh.h[(s + 1) & 1];
        float hv2[16];
        #pragma unroll
        for (int q = 0; q < 4; ++q) {
          float4 v = nh4[(4 * ln + q) ^ (ln & 7)];
          hv2[q*4+0] = v.x; hv2[q*4+1] = v.y; hv2[q*4+2] = v.z; hv2[q*4+3] = v.w;
        }
        #pragma unroll
        for (int r = 0; r < OUTD; ++r) {
          const float4* wo = (const float4*)&oW[(size_t)r * HID + ln * 16];
          float4 q0 = wo[0], q1 = wo[1], q2 = wo[2], q3 = wo[3];
          float acc = 0.f;
          acc = fmaf(q0.x, hv2[ 0], acc); acc = fmaf(q0.y, hv2[ 1], acc);
          acc = fmaf(q0.z, hv2[ 2], acc); acc = fmaf(q0.w, hv2[ 3], acc);
          acc = fmaf(q1.x, hv2[ 4], acc); acc = fmaf(q1.y, hv2[ 5], acc);
          acc = fmaf(q1.z, hv2[ 6], acc); acc = fmaf(q1.w, hv2[ 7], acc);
          acc = fmaf(q2.x, hv2[ 8], acc); acc = fmaf(q2.y, hv2[ 9], acc);
          acc = fmaf(q2.z, hv2[10], acc); acc = fmaf(q2.w, hv2[11], acc);
          acc = fmaf(q3.x, hv2[12], acc); acc = fmaf(q3.y, hv2[13], acc);
          acc = fmaf(q3.z, hv2[14], acc); acc = fmaf(q3.w, hv2[15], acc);
          #pragma unroll
          for (int off = 32; off > 0; off >>= 1) acc += __shfl_xor(acc, off);
          if (ln == 0) sh.predv[r] = acc + ob[r];
        }
      }
      __syncthreads();
      if (tid == 0) {
        float rr = rintf(sh.predv[0]);                    // jnp.round: half-to-even
        rr = fminf(fmaxf(rr, 0.0f), (float)(VOCAB - 1));
        int nv = (int)rr;
        sh.nid = nv;
        sh.sdone = (nv == EOSTOK) ? 1 : 0;
        #pragma unroll
        for (int q = 0; q < OUTD; ++q) out[s * OUTD + q] = sh.predv[q];
        out[OUTD * MAXLEN + s] = 1.0f;                    // valids[s]
      }
      __syncthreads();
      {
        int nv = sh.nid;                                  // emb[PAD] row is zero
        unsigned tagw = (unsigned)(s + 1) | (sh.sdone ? DONEBIT : 0u);
        ull* ebp = ep + ((s + 1) & 1) * EMBD;
        int c2 = tid * 2;
        float e0 = emb[(size_t)nv * EMBD + c2 + 0];
        float e1 = emb[(size_t)nv * EMBD + c2 + 1];
        stA(&ebp[c2 + 0], ((ull)tagw << 32) | (ull)__float_as_uint(e0));
        stA(&ebp[c2 + 1], ((ull)tagw << 32) | (ull)__float_as_uint(e1));
      }
    }
  }
}

extern "C" void kernel_launch(void* const* d_in, const int* in_sizes, int n_in,
                              void* d_out, int out_size, void* d_ws, size_t ws_size,
                              hipStream_t stream) {
  (void)in_sizes; (void)n_in; (void)out_size; (void)ws_size;
  hipLaunchKernelGGL(s2s_kernel, dim3(NBLK), dim3(NTHR), 0, stream,
                     (const int*)d_in[0],  (const float*)d_in[1],
                     (const float*)d_in[2], (const float*)d_in[3],
                     (const float*)d_in[4], (const float*)d_in[5],
                     (const float*)d_in[6], (const float*)d_in[7],
                     (const float*)d_in[8], (const float*)d_in[9],
                     (const float*)d_in[10], (const float*)d_in[11],
                     (float*)d_out, (char*)d_ws);
}

// Round 3
// 4279.826 us; speedup vs baseline: 2.2317x; 2.2317x over previous
//
#include <hip/hip_runtime.h>
#include <stdint.h>

typedef unsigned long long ull;

#define VOCAB   50000
#define EMBD    512
#define HID     1024
#define SEQ     2048
#define OUTD    5
#define MAXLEN  20
#define SOSTOK  1
#define EOSTOK  2

#define NBLK 256
#define NTHR 256

#define DONEBIT 0x40000000u
#define TAGMSK  0x3FFFFFFFu
#define SPINMAX (1 << 22)

// Opaque register pin: prevents the compiler from sinking/rematerializing
// the weight loads into the recurrence loop (round-2 showed VGPR_Count=96,
// i.e. weights were being re-streamed from L2/MALL every step).
#define PIN(x) asm volatile("" : "+v"(x))

struct alignas(16) SharedR {
  float h[2][HID];
  float e[2][EMBD];
  float predv[OUTD];
  int   nid;
  int   sdone;
};

__device__ __forceinline__ float sigf(float x)      { return 1.0f / (1.0f + __expf(-x)); }
__device__ __forceinline__ float tanh_fast(float x) { return 1.0f - 2.0f / (__expf(2.0f * x) + 1.0f); }

// Tagged-cell ops: AGENT scope -> coherent across XCDs.
__device__ __forceinline__ ull ldA(ull* p) {
  return __hip_atomic_load(p, __ATOMIC_RELAXED, __HIP_MEMORY_SCOPE_AGENT);
}
__device__ __forceinline__ void stA(ull* p, ull v) {
  __hip_atomic_store(p, v, __ATOMIC_RELAXED, __HIP_MEMORY_SCOPE_AGENT);
}

// Combined concurrent spin: re-issue ALL mismatched cells each round so the
// whole poll costs ~1 MALL round-trip, not 4 chained ones. Bounded so a
// protocol bug becomes a fast wrong answer, not a hang.
__device__ __forceinline__ void spin4(ull& v0, ull& v1, ull& v2, ull& v3,
                                      ull* p0, ull* p1, ull* p2, ull* p3,
                                      unsigned tg) {
  int n = 0;
  while (n++ <= SPINMAX) {
    bool m0 = ((unsigned)(v0 >> 32) == tg);
    bool m1 = ((unsigned)(v1 >> 32) == tg);
    bool m2 = ((unsigned)(v2 >> 32) == tg);
    bool m3 = ((unsigned)(v3 >> 32) == tg);
    if (m0 & m1 & m2 & m3) break;
    if (!m0) v0 = ldA(p0);
    if (!m1) v1 = ldA(p1);
    if (!m2) v2 = ldA(p2);
    if (!m3) v3 = ldA(p3);
  }
}

__device__ __forceinline__ void spin2(ull& v0, ull& v1, ull* p0, ull* p1,
                                      unsigned tg, unsigned msk) {
  int n = 0;
  while (n++ <= SPINMAX) {
    bool m0 = (((unsigned)(v0 >> 32) & msk) == tg);
    bool m1 = (((unsigned)(v1 >> 32) & msk) == tg);
    if (m0 & m1) break;
    if (!m0) v0 = ldA(p0);
    if (!m1) v1 = ldA(p1);
  }
}

__global__ __launch_bounds__(NTHR, 1) void s2s_kernel(
    const int*   __restrict__ x,
    const float* __restrict__ emb,
    const float* __restrict__ eWih, const float* __restrict__ eWhh,
    const float* __restrict__ ebih, const float* __restrict__ ebhh,
    const float* __restrict__ dWih, const float* __restrict__ dWhh,
    const float* __restrict__ dbih, const float* __restrict__ dbhh,
    const float* __restrict__ oW,   const float* __restrict__ ob,
    float* __restrict__ out, char* __restrict__ ws)
{
  const int b   = blockIdx.x;
  const int tid = threadIdx.x;
  const int wv  = tid >> 6;
  const int ln  = tid & 63;
  const int j   = 4 * b + wv;          // h index owned by this wave (0..1023)

  // Double-buffered tagged cells (parity = tag&1): no producer can overwrite
  // a buffer until every block has consumed the previous tag in it.
  ull* hp = (ull*)ws;                        // [2][HID]  (tag<<32)|h_bits
  ull* ep = (ull*)(ws + 2 * HID * 8);        // [2][EMBD] (tag<<32)|e_bits

  __shared__ SharedR sh;

  // ---- encoder weights resident in registers for the whole recurrence ----
  float wr[4][16];   // eWhh[g*HID+j][16*ln + m]
  float wi[4][8];    // eWih[g*HID+j][ 8*ln + m]
  #pragma unroll
  for (int g = 0; g < 4; ++g) {
    const float4* ph = (const float4*)&eWhh[(size_t)(g * HID + j) * HID + ln * 16];
    #pragma unroll
    for (int q = 0; q < 4; ++q) {
      float4 v = ph[q];
      wr[g][q*4+0] = v.x; wr[g][q*4+1] = v.y; wr[g][q*4+2] = v.z; wr[g][q*4+3] = v.w;
    }
    const float4* pw = (const float4*)&eWih[(size_t)(g * HID + j) * EMBD + ln * 8];
    #pragma unroll
    for (int q = 0; q < 2; ++q) {
      float4 v = pw[q];
      wi[g][q*4+0] = v.x; wi[g][q*4+1] = v.y; wi[g][q*4+2] = v.z; wi[g][q*4+3] = v.w;
    }
  }
  float bse[4], bsd[4];
  if (ln == 0) {
    #pragma unroll
    for (int g = 0; g < 4; ++g) {
      int r = g * HID + j;
      bse[g] = ebih[r] + ebhh[r];
      bsd[g] = dbih[r] + dbhh[r];
    }
  }
  // Pin every weight/bias in a VGPR (see PIN comment above).
  #pragma unroll
  for (int g = 0; g < 4; ++g) {
    #pragma unroll
    for (int m = 0; m < 16; ++m) PIN(wr[g][m]);
    #pragma unroll
    for (int m = 0; m < 8; ++m)  PIN(wi[g][m]);
    PIN(bse[g]); PIN(bsd[g]);
  }

  // h0 = 0
  for (int i = tid; i < HID; i += NTHR) sh.h[0][i] = 0.f;
  float creg = 0.f;                    // cell state (lane 0 of each wave)

  // Software-pipelined embedding row: prefetch step t's row during step t-1,
  // so its MALL/HBM latency is off the critical path. emb[PAD] row is zero.
  float2 ein;
  {
    int xv0 = x[0];
    ein = *(const float2*)&emb[(size_t)xv0 * EMBD + tid * 2];
  }

  // ============================ ENCODER ============================
  #pragma unroll 1
  for (int t = 1; t <= SEQ; ++t) {
    // stage this step's e into LDS (value prefetched last iteration)
    {
      float* eb = sh.e[(t - 1) & 1];
      int gp = (tid >> 1) ^ ((tid >> 3) & 7);
      int lo = (tid & 1) * 2;
      eb[gp * 4 + lo + 0] = ein.x;
      eb[gp * 4 + lo + 1] = ein.y;
    }
    // prefetch next step's row (full poll+compute time to complete)
    float2 ein_nx = make_float2(0.f, 0.f);
    if (t < SEQ) {
      int xv = x[t];
      ein_nx = *(const float2*)&emb[(size_t)xv * EMBD + tid * 2];
    }

    if (t > 1) {                       // poll h_{t-1} from buffer (t-1)&1
      unsigned tg = (unsigned)(t - 1);
      ull* hb = hp + ((t - 1) & 1) * HID;
      int c = tid * 4;
      ull v0 = ldA(&hb[c+0]), v1 = ldA(&hb[c+1]), v2 = ldA(&hb[c+2]), v3 = ldA(&hb[c+3]);
      spin4(v0, v1, v2, v3, &hb[c+0], &hb[c+1], &hb[c+2], &hb[c+3], tg);
      float4 hv4;
      hv4.x = __uint_as_float((unsigned)v0);
      hv4.y = __uint_as_float((unsigned)v1);
      hv4.z = __uint_as_float((unsigned)v2);
      hv4.w = __uint_as_float((unsigned)v3);
      ((float4*)sh.h[(t - 1) & 1])[tid ^ ((tid >> 2) & 7)] = hv4;
    }
    __syncthreads();

    const float4* h4 = (const float4*)sh.h[(t - 1) & 1];
    const float4* e4 = (const float4*)sh.e[(t - 1) & 1];
    float hv[16], ev[8];
    #pragma unroll
    for (int q = 0; q < 4; ++q) {
      float4 v = h4[(4 * ln + q) ^ (ln & 7)];
      hv[q*4+0] = v.x; hv[q*4+1] = v.y; hv[q*4+2] = v.z; hv[q*4+3] = v.w;
    }
    #pragma unroll
    for (int q = 0; q < 2; ++q) {
      float4 v = e4[(2 * ln + q) ^ ((ln >> 1) & 7)];
      ev[q*4+0] = v.x; ev[q*4+1] = v.y; ev[q*4+2] = v.z; ev[q*4+3] = v.w;
    }
    float a0 = 0.f, a1 = 0.f, a2 = 0.f, a3 = 0.f;
    #pragma unroll
    for (int m = 0; m < 16; ++m) {
      a0 = fmaf(wr[0][m], hv[m], a0);
      a1 = fmaf(wr[1][m], hv[m], a1);
      a2 = fmaf(wr[2][m], hv[m], a2);
      a3 = fmaf(wr[3][m], hv[m], a3);
    }
    #pragma unroll
    for (int m = 0; m < 8; ++m) {
      a0 = fmaf(wi[0][m], ev[m], a0);
      a1 = fmaf(wi[1][m], ev[m], a1);
      a2 = fmaf(wi[2][m], ev[m], a2);
      a3 = fmaf(wi[3][m], ev[m], a3);
    }
    #pragma unroll
    for (int off = 32; off > 0; off >>= 1) {
      a0 += __shfl_xor(a0, off);
      a1 += __shfl_xor(a1, off);
      a2 += __shfl_xor(a2, off);
      a3 += __shfl_xor(a3, off);
    }
    if (ln == 0) {                      // gate order i,f,g,o
      float iv = sigf(a0 + bse[0]);
      float fv = sigf(a1 + bse[1]);
      float gv = tanh_fast(a2 + bse[2]);
      float ov = sigf(a3 + bse[3]);
      creg = fv * creg + iv * gv;
      float hn = ov * tanh_fast(creg);
      stA(&hp[(t & 1) * HID + j], ((ull)(unsigned)t << 32) | (ull)__float_as_uint(hn));
    }
    ein = ein_nx;
  }

  // ============================ DECODER ============================
  #pragma unroll 1
  for (int s = 0; s < MAXLEN; ++s) {
    // ---- input embedding ----
    if (s == 0) {
      if (tid < 128) {
        const float4* se = (const float4*)&emb[SOSTOK * EMBD];
        ((float4*)sh.e[0])[tid ^ ((tid >> 2) & 7)] = se[tid];
      }
      if (tid == 0) sh.sdone = 0;
    } else {
      unsigned tg = (unsigned)s;
      ull* eb = ep + (s & 1) * EMBD;
      int c = tid * 2;
      ull v0 = ldA(&eb[c+0]), v1 = ldA(&eb[c+1]);
      spin2(v0, v1, &eb[c+0], &eb[c+1], tg, TAGMSK);
      if (tid == 0) sh.sdone = (((unsigned)(v0 >> 32)) & DONEBIT) ? 1 : 0;
      float* ebl = sh.e[s & 1];
      int gp = (tid >> 1) ^ ((tid >> 3) & 7);
      int lo = (tid & 1) * 2;
      ebl[gp * 4 + lo + 0] = __uint_as_float((unsigned)v0);
      ebl[gp * 4 + lo + 1] = __uint_as_float((unsigned)v1);
    }
    // ---- poll h input (tag SEQ+s, buffer s&1; s=0 reuses encoder-final 2048) ----
    {
      unsigned tg = (unsigned)(SEQ + s);
      ull* hb = hp + (s & 1) * HID;
      int c = tid * 4;
      ull v0 = ldA(&hb[c+0]), v1 = ldA(&hb[c+1]), v2 = ldA(&hb[c+2]), v3 = ldA(&hb[c+3]);
      spin4(v0, v1, v2, v3, &hb[c+0], &hb[c+1], &hb[c+2], &hb[c+3], tg);
      float4 hv4;
      hv4.x = __uint_as_float((unsigned)v0);
      hv4.y = __uint_as_float((unsigned)v1);
      hv4.z = __uint_as_float((unsigned)v2);
      hv4.w = __uint_as_float((unsigned)v3);
      ((float4*)sh.h[s & 1])[tid ^ ((tid >> 2) & 7)] = hv4;
    }
    __syncthreads();
    if (s > 0 && sh.sdone) {
      if (b == 0) {   // zero-fill remaining rows + valids, then stop
        for (int i = s * OUTD + tid; i < OUTD * MAXLEN; i += NTHR) out[i] = 0.f;
        for (int i = s + tid; i < MAXLEN; i += NTHR) out[OUTD * MAXLEN + i] = 0.f;
      }
      break;
    }

    const float4* h4 = (const float4*)sh.h[s & 1];
    const float4* e4 = (const float4*)sh.e[s & 1];
    float hv[16], ev[8];
    #pragma unroll
    for (int q = 0; q < 4; ++q) {
      float4 v = h4[(4 * ln + q) ^ (ln & 7)];
      hv[q*4+0] = v.x; hv[q*4+1] = v.y; hv[q*4+2] = v.z; hv[q*4+3] = v.w;
    }
    #pragma unroll
    for (int q = 0; q < 2; ++q) {
      float4 v = e4[(2 * ln + q) ^ ((ln >> 1) & 7)];
      ev[q*4+0] = v.x; ev[q*4+1] = v.y; ev[q*4+2] = v.z; ev[q*4+3] = v.w;
    }
    float ag[4];
    #pragma unroll
    for (int g = 0; g < 4; ++g) {
      size_t row = (size_t)(g * HID + j);
      const float4* wh = (const float4*)&dWhh[row * HID + ln * 16];
      const float4* wu = (const float4*)&dWih[row * EMBD + ln * 8];
      float4 w0 = wh[0], w1 = wh[1], w2 = wh[2], w3 = wh[3];
      float4 u0 = wu[0], u1 = wu[1];
      float acc = 0.f;
      acc = fmaf(w0.x, hv[ 0], acc); acc = fmaf(w0.y, hv[ 1], acc);
      acc = fmaf(w0.z, hv[ 2], acc); acc = fmaf(w0.w, hv[ 3], acc);
      acc = fmaf(w1.x, hv[ 4], acc); acc = fmaf(w1.y, hv[ 5], acc);
      acc = fmaf(w1.z, hv[ 6], acc); acc = fmaf(w1.w, hv[ 7], acc);
      acc = fmaf(w2.x, hv[ 8], acc); acc = fmaf(w2.y, hv[ 9], acc);
      acc = fmaf(w2.z, hv[10], acc); acc = fmaf(w2.w, hv[11], acc);
      acc = fmaf(w3.x, hv[12], acc); acc = fmaf(w3.y, hv[13], acc);
      acc = fmaf(w3.z, hv[14], acc); acc = fmaf(w3.w, hv[15], acc);
      acc = fmaf(u0.x, ev[ 0], acc); acc = fmaf(u0.y, ev[ 1], acc);
      acc = fmaf(u0.z, ev[ 2], acc); acc = fmaf(u0.w, ev[ 3], acc);
      acc = fmaf(u1.x, ev[ 4], acc); acc = fmaf(u1.y, ev[ 5], acc);
      acc = fmaf(u1.z, ev[ 6], acc); acc = fmaf(u1.w, ev[ 7], acc);
      ag[g] = acc;
    }
    #pragma unroll
    for (int off = 32; off > 0; off >>= 1) {
      ag[0] += __shfl_xor(ag[0], off);
      ag[1] += __shfl_xor(ag[1], off);
      ag[2] += __shfl_xor(ag[2], off);
      ag[3] += __shfl_xor(ag[3], off);
    }
    if (ln == 0) {
      float iv = sigf(ag[0] + bsd[0]);
      float fv = sigf(ag[1] + bsd[1]);
      float gv = tanh_fast(ag[2] + bsd[2]);
      float ov = sigf(ag[3] + bsd[3]);
      creg = fv * creg + iv * gv;
      float hn = ov * tanh_fast(creg);
      stA(&hp[((s + 1) & 1) * HID + j],
          ((ull)(unsigned)(SEQ + 1 + s) << 32) | (ull)__float_as_uint(hn));
    }

    // ---- block 0: output projection, token decision, next-emb publish ----
    if (b == 0) {
      unsigned tg = (unsigned)(SEQ + 1 + s);
      ull* hb = hp + ((s + 1) & 1) * HID;
      int c = tid * 4;
      ull v0 = ldA(&hb[c+0]), v1 = ldA(&hb[c+1]), v2 = ldA(&hb[c+2]), v3 = ldA(&hb[c+3]);
      spin4(v0, v1, v2, v3, &hb[c+0], &hb[c+1], &hb[c+2], &hb[c+3], tg);
      float4 hv4;
      hv4.x = __uint_as_float((unsigned)v0);
      hv4.y = __uint_as_float((unsigned)v1);
      hv4.z = __uint_as_float((unsigned)v2);
      hv4.w = __uint_as_float((unsigned)v3);
      ((float4*)sh.h[(s + 1) & 1])[tid ^ ((tid >> 2) & 7)] = hv4;
      __syncthreads();
      if (wv == 0) {
        const float4* nh4 = (const float4*)sh.h[(s + 1) & 1];
        float hv2[16];
        #pragma unroll
        for (int q = 0; q < 4; ++q) {
          float4 v = nh4[(4 * ln + q) ^ (ln & 7)];
          hv2[q*4+0] = v.x; hv2[q*4+1] = v.y; hv2[q*4+2] = v.z; hv2[q*4+3] = v.w;
        }
        #pragma unroll
        for (int r = 0; r < OUTD; ++r) {
          const float4* wo = (const float4*)&oW[(size_t)r * HID + ln * 16];
          float4 q0 = wo[0], q1 = wo[1], q2 = wo[2], q3 = wo[3];
          float acc = 0.f;
          acc = fmaf(q0.x, hv2[ 0], acc); acc = fmaf(q0.y, hv2[ 1], acc);
          acc = fmaf(q0.z, hv2[ 2], acc); acc = fmaf(q0.w, hv2[ 3], acc);
          acc = fmaf(q1.x, hv2[ 4], acc); acc = fmaf(q1.y, hv2[ 5], acc);
          acc = fmaf(q1.z, hv2[ 6], acc); acc = fmaf(q1.w, hv2[ 7], acc);
          acc = fmaf(q2.x, hv2[ 8], acc); acc = fmaf(q2.y, hv2[ 9], acc);
          acc = fmaf(q2.z, hv2[10], acc); acc = fmaf(q2.w, hv2[11], acc);
          acc = fmaf(q3.x, hv2[12], acc); acc = fmaf(q3.y, hv2[13], acc);
          acc = fmaf(q3.z, hv2[14], acc); acc = fmaf(q3.w, hv2[15], acc);
          #pragma unroll
          for (int off = 32; off > 0; off >>= 1) acc += __shfl_xor(acc, off);
          if (ln == 0) sh.predv[r] = acc + ob[r];
        }
      }
      __syncthreads();
      if (tid == 0) {
        float rr = rintf(sh.predv[0]);                    // jnp.round: half-to-even
        rr = fminf(fmaxf(rr, 0.0f), (float)(VOCAB - 1));
        int nv = (int)rr;
        sh.nid = nv;
        sh.sdone = (nv == EOSTOK) ? 1 : 0;
        #pragma unroll
        for (int q = 0; q < OUTD; ++q) out[s * OUTD + q] = sh.predv[q];
        out[OUTD * MAXLEN + s] = 1.0f;                    // valids[s]
      }
      __syncthreads();
      {
        int nv = sh.nid;                                  // emb[PAD] row is zero
        unsigned tagw = (unsigned)(s + 1) | (sh.sdone ? DONEBIT : 0u);
        ull* ebp = ep + ((s + 1) & 1) * EMBD;
        int c2 = tid * 2;
        float e0 = emb[(size_t)nv * EMBD + c2 + 0];
        float e1 = emb[(size_t)nv * EMBD + c2 + 1];
        stA(&ebp[c2 + 0], ((ull)tagw << 32) | (ull)__float_as_uint(e0));
        stA(&ebp[c2 + 1], ((ull)tagw << 32) | (ull)__float_as_uint(e1));
      }
    }
  }
}

extern "C" void kernel_launch(void* const* d_in, const int* in_sizes, int n_in,
                              void* d_out, int out_size, void* d_ws, size_t ws_size,
                              hipStream_t stream) {
  (void)in_sizes; (void)n_in; (void)out_size; (void)ws_size;
  hipLaunchKernelGGL(s2s_kernel, dim3(NBLK), dim3(NTHR), 0, stream,
                     (const int*)d_in[0],  (const float*)d_in[1],
                     (const float*)d_in[2], (const float*)d_in[3],
                     (const float*)d_in[4], (const float*)d_in[5],
                     (const float*)d_in[6], (const float*)d_in[7],
                     (const float*)d_in[8], (const float*)d_in[9],
                     (const float*)d_in[10], (const float*)d_in[11],
                     (float*)d_out, (char*)d_ws);
}